// Round 1
// baseline (7757.240 us; speedup 1.0000x reference)
//
#include <hip/hip_runtime.h>
#include <math.h>

#define D512 512
#define BM 64
#define BN 64
#define BK 16

__device__ __forceinline__ float sigmoidf_(float z){ return 1.0f/(1.0f+expf(-z)); }
__device__ __forceinline__ float siluf_(float z){ return z/(1.0f+expf(-z)); }
__device__ __forceinline__ float dsiluf_(float z){ float s=1.0f/(1.0f+expf(-z)); return s*(1.0f+z*(1.0f-s)); }

// ---- LDS staging helpers (all operands have row stride 512 floats) ----
// NT-style: operand row-major, contraction along the contiguous dim.
// S[k][i] = base[i*512 + k]  (base already offset to tile row0 and k0)
__device__ __forceinline__ void stage_nt(const float* __restrict__ base, float S[BK][BM], int tid){
  const int li = tid >> 2;          // 0..63 tile row
  const int lk = (tid & 3) * 4;     // 0..12 k quad
  const float4 v = *(const float4*)(base + (size_t)li * D512 + lk);
  S[lk+0][li] = v.x; S[lk+1][li] = v.y; S[lk+2][li] = v.z; S[lk+3][li] = v.w;
}

// NN-style: contraction along the row dim; tile columns contiguous.
// S[r][c] = base[r*512 + c]  (base already offset to k0 row and tile col0)
__device__ __forceinline__ void stage_nn(const float* __restrict__ base, float S[BK][BN], int tid){
  const int lr = tid >> 4;          // 0..15
  const int lc = (tid & 15) * 4;    // 0..60
  const float4 v = *(const float4*)(base + (size_t)lr * D512 + lc);
  *(float4*)&S[lr][lc] = v;
}

__device__ __forceinline__ void mm_tile(const float As[BK][BM], const float Bs[BK][BN],
                                        float acc[4][4], int ty, int tx){
#pragma unroll
  for (int kk = 0; kk < BK; kk++){
    const float4 a4 = *(const float4*)&As[kk][ty*4];
    const float4 b4 = *(const float4*)&Bs[kk][tx*4];
    const float a[4] = {a4.x, a4.y, a4.z, a4.w};
    const float b[4] = {b4.x, b4.y, b4.z, b4.w};
#pragma unroll
    for (int ii = 0; ii < 4; ii++)
#pragma unroll
      for (int jj = 0; jj < 4; jj++)
        acc[ii][jj] += a[ii] * b[jj];
  }
}

// ---------------- big GEMMs ----------------
// C[i,j] = (silu?)( sum_k A[i,k] * B[j,k] ), A [M,512] row-major, B [512,512] row-major
template<bool SILU>
__global__ __launch_bounds__(256) void gemm_nt(const float* __restrict__ A,
                                               const float* __restrict__ B,
                                               float* __restrict__ C){
  __shared__ float As[BK][BM];
  __shared__ float Bs[BK][BN];
  const int tid = threadIdx.x, tx = tid & 15, ty = tid >> 4;
  const size_t arow = (size_t)blockIdx.y * BM;
  const size_t bcol = (size_t)blockIdx.x * BN;
  float acc[4][4] = {};
  for (int k0 = 0; k0 < D512; k0 += BK){
    stage_nt(A + arow * D512 + k0, As, tid);
    stage_nt(B + bcol * D512 + k0, Bs, tid);
    __syncthreads();
    mm_tile(As, Bs, acc, ty, tx);
    __syncthreads();
  }
#pragma unroll
  for (int ii = 0; ii < 4; ii++){
    float4 o;
    if (SILU){ o.x=siluf_(acc[ii][0]); o.y=siluf_(acc[ii][1]); o.z=siluf_(acc[ii][2]); o.w=siluf_(acc[ii][3]); }
    else     { o.x=acc[ii][0]; o.y=acc[ii][1]; o.z=acc[ii][2]; o.w=acc[ii][3]; }
    *(float4*)(C + (arow + ty*4 + ii) * D512 + bcol + tx*4) = o;
  }
}

// xm[b,i,e] = sum_d x_store[b,i,d] * M[b][d,e]   (NN, batched via blockIdx.z)
__global__ __launch_bounds__(256) void gemm_nn_batched(const float* __restrict__ A,
                                                       const float* __restrict__ B,
                                                       float* __restrict__ C){
  const int b = blockIdx.z;
  A += (size_t)b * 4096 * D512;
  C += (size_t)b * 4096 * D512;
  B += (size_t)b * D512 * D512;
  __shared__ float As[BK][BM];
  __shared__ float Bs[BK][BN];
  const int tid = threadIdx.x, tx = tid & 15, ty = tid >> 4;
  const size_t arow = (size_t)blockIdx.y * BM;
  const size_t bcol = (size_t)blockIdx.x * BN;
  float acc[4][4] = {};
  for (int k0 = 0; k0 < D512; k0 += BK){
    stage_nt(A + arow * D512 + k0, As, tid);
    stage_nn(B + (size_t)k0 * D512 + bcol, Bs, tid);
    __syncthreads();
    mm_tile(As, Bs, acc, ty, tx);
    __syncthreads();
  }
#pragma unroll
  for (int ii = 0; ii < 4; ii++){
    float4 o; o.x=acc[ii][0]; o.y=acc[ii][1]; o.z=acc[ii][2]; o.w=acc[ii][3];
    *(float4*)(C + (arow + ty*4 + ii) * D512 + bcol + tx*4) = o;
  }
}

// ---------------- small pre-kernels ----------------
__global__ void chunk_mean_kernel(const float* __restrict__ x, float* __restrict__ cm){
  const int c = blockIdx.x, b = blockIdx.y, tid = threadIdx.x; // 128 threads
  const float* base = x + ((size_t)b * 4096 + (size_t)c * 64) * D512 + tid * 4;
  float4 s = {0,0,0,0};
  for (int r = 0; r < 64; r++){
    const float4 v = *(const float4*)(base + (size_t)r * D512);
    s.x += v.x; s.y += v.y; s.z += v.z; s.w += v.w;
  }
  const float inv = 1.0f / 64.0f;
  s.x *= inv; s.y *= inv; s.z *= inv; s.w *= inv;
  *(float4*)(cm + ((size_t)b * 64 + c) * D512 + tid * 4) = s;
}

__global__ void gates_kernel(const float* __restrict__ cm,
                             const float* __restrict__ Wgd, const float* __restrict__ bgd,
                             const float* __restrict__ Wgl, const float* __restrict__ bgl,
                             const float* __restrict__ Wgm, const float* __restrict__ bgm,
                             float* __restrict__ alpha, float* __restrict__ theta, float* __restrict__ eta){
  const int c = blockIdx.x, tid = threadIdx.x; // 256 threads
  __shared__ float cmsh[512];
  float s0 = 0.f, s1 = 0.f, s2 = 0.f;
  for (int b = 0; b < 4; b++){
    __syncthreads();
    if (tid < 128){
      const float4 v = *(const float4*)(cm + ((size_t)b * 64 + c) * D512 + tid * 4);
      *(float4*)&cmsh[tid * 4] = v;
    }
    __syncthreads();
    for (int j = tid; j < 512; j += 256){
      float d0 = bgd[j], d1 = bgl[j], d2 = bgm[j];
      const float* w0 = Wgd + (size_t)j * D512;
      const float* w1 = Wgl + (size_t)j * D512;
      const float* w2 = Wgm + (size_t)j * D512;
      for (int kk = 0; kk < 512; kk += 4){
        const float4 cv = *(const float4*)&cmsh[kk];
        const float4 a = *(const float4*)(w0 + kk); d0 += cv.x*a.x + cv.y*a.y + cv.z*a.z + cv.w*a.w;
        const float4 e = *(const float4*)(w1 + kk); d1 += cv.x*e.x + cv.y*e.y + cv.z*e.z + cv.w*e.w;
        const float4 g = *(const float4*)(w2 + kk); d2 += cv.x*g.x + cv.y*g.y + cv.z*g.z + cv.w*g.w;
      }
      s0 += sigmoidf_(d0); s1 += sigmoidf_(d1); s2 += sigmoidf_(d2);
    }
  }
  __shared__ float red[256];
  const float inv = 1.0f / 2048.0f; // mean over 4 batches * 512 outputs
  // alpha
  red[tid] = s0; __syncthreads();
  for (int o = 128; o > 0; o >>= 1){ if (tid < o) red[tid] += red[tid + o]; __syncthreads(); }
  if (tid == 0) alpha[c] = red[0] * inv * 0.01f;
  __syncthreads();
  red[tid] = s1; __syncthreads();
  for (int o = 128; o > 0; o >>= 1){ if (tid < o) red[tid] += red[tid + o]; __syncthreads(); }
  if (tid == 0) theta[c] = red[0] * inv * 0.1f;
  __syncthreads();
  red[tid] = s2; __syncthreads();
  for (int o = 128; o > 0; o >>= 1){ if (tid < o) red[tid] += red[tid + o]; __syncthreads(); }
  if (tid == 0) eta[c] = red[0] * inv * 0.9f;
}

__global__ void rmsnorm2_kernel(const float* __restrict__ x,
                                const float* __restrict__ gs, const float* __restrict__ gr,
                                float* __restrict__ xs, float* __restrict__ xr){
  const size_t row = blockIdx.x; const int tid = threadIdx.x; // 128 threads
  const float4 xv = *(const float4*)(x + row * D512 + tid * 4);
  float ss = xv.x*xv.x + xv.y*xv.y + xv.z*xv.z + xv.w*xv.w;
  for (int o = 32; o > 0; o >>= 1) ss += __shfl_xor(ss, o, 64);
  __shared__ float w2[2];
  if ((tid & 63) == 0) w2[tid >> 6] = ss;
  __syncthreads();
  const float tot = w2[0] + w2[1];
  const float r = rsqrtf(tot * (1.0f / 512.0f) + 1.1920929e-07f);
  const float4 g1 = *(const float4*)(gs + tid * 4);
  const float4 g2 = *(const float4*)(gr + tid * 4);
  float4 o1, o2;
  o1.x = xv.x*r*g1.x; o1.y = xv.y*r*g1.y; o1.z = xv.z*r*g1.z; o1.w = xv.w*r*g1.w;
  o2.x = xv.x*r*g2.x; o2.y = xv.y*r*g2.y; o2.z = xv.z*r*g2.z; o2.w = xv.w*r*g2.w;
  *(float4*)(xs + row * D512 + tid * 4) = o1;
  *(float4*)(xr + row * D512 + tid * 4) = o2;
}

__global__ void l2norm_kernel(float* __restrict__ buf){
  const size_t row = blockIdx.x; const int tid = threadIdx.x; // 128 threads
  float4 xv = *(const float4*)(buf + row * D512 + tid * 4);
  float ss = xv.x*xv.x + xv.y*xv.y + xv.z*xv.z + xv.w*xv.w;
  for (int o = 32; o > 0; o >>= 1) ss += __shfl_xor(ss, o, 64);
  __shared__ float w2[2];
  if ((tid & 63) == 0) w2[tid >> 6] = ss;
  __syncthreads();
  const float n = sqrtf(w2[0] + w2[1]);
  const float sc = 1.0f / fmaxf(n, 1e-12f);
  xv.x *= sc; xv.y *= sc; xv.z *= sc; xv.w *= sc;
  *(float4*)(buf + row * D512 + tid * 4) = xv;
}

// ---------------- scan kernels ----------------
// Row mapping: within chunk t, logical row i in [0,256): global row = (i>>6)*4096 + t*64 + (i&63).
// Tiles are 64 rows => blockIdx.y == batch index, rows contiguous.

// z=0: pre = k_chunk @ W0^T -> pre0 (dense) and hk = silu(pre)
// z=1: hq = silu(q_chunk @ W0^T)
__global__ __launch_bounds__(256) void scan_fw0(const float* __restrict__ kbuf,
                                                const float* __restrict__ qbuf,
                                                const float* __restrict__ W0,
                                                float* __restrict__ pre0,
                                                float* __restrict__ hk,
                                                float* __restrict__ hq, int t){
  __shared__ float As[BK][BM];
  __shared__ float Bs[BK][BN];
  const int tid = threadIdx.x, tx = tid & 15, ty = tid >> 4;
  const int bt = blockIdx.y, z = blockIdx.z;
  const float* src = z ? qbuf : kbuf;
  const float* Abase = src + ((size_t)bt * 4096 + (size_t)t * 64) * D512;
  const size_t bcol = (size_t)blockIdx.x * BN;
  float acc[4][4] = {};
  for (int k0 = 0; k0 < D512; k0 += BK){
    stage_nt(Abase + k0, As, tid);
    stage_nt(W0 + bcol * D512 + k0, Bs, tid);
    __syncthreads();
    mm_tile(As, Bs, acc, ty, tx);
    __syncthreads();
  }
  const size_t orow0 = (size_t)bt * 64;
#pragma unroll
  for (int ii = 0; ii < 4; ii++){
    const size_t off = (orow0 + ty*4 + ii) * D512 + bcol + tx*4;
    float4 p; p.x=acc[ii][0]; p.y=acc[ii][1]; p.z=acc[ii][2]; p.w=acc[ii][3];
    float4 h; h.x=siluf_(p.x); h.y=siluf_(p.y); h.z=siluf_(p.z); h.w=siluf_(p.w);
    if (z == 0){ *(float4*)(pre0 + off) = p; *(float4*)(hk + off) = h; }
    else       { *(float4*)(hq + off) = h; }
  }
}

// z=0: e = (hk @ W1^T - v_chunk) * 2/131072 -> ebuf (dense)
// z=1: retrieved_chunk = hq @ W1^T (mapped rows)
__global__ __launch_bounds__(256) void scan_fw1(const float* __restrict__ hk,
                                                const float* __restrict__ hq,
                                                const float* __restrict__ W1,
                                                const float* __restrict__ vbuf,
                                                float* __restrict__ ebuf,
                                                float* __restrict__ ret, int t){
  __shared__ float As[BK][BM];
  __shared__ float Bs[BK][BN];
  const int tid = threadIdx.x, tx = tid & 15, ty = tid >> 4;
  const int bt = blockIdx.y, z = blockIdx.z;
  const float* Abase = (z ? hq : hk) + (size_t)bt * 64 * D512;
  const size_t bcol = (size_t)blockIdx.x * BN;
  float acc[4][4] = {};
  for (int k0 = 0; k0 < D512; k0 += BK){
    stage_nt(Abase + k0, As, tid);
    stage_nt(W1 + bcol * D512 + k0, Bs, tid);
    __syncthreads();
    mm_tile(As, Bs, acc, ty, tx);
    __syncthreads();
  }
  if (z == 0){
    const float* vbase = vbuf + ((size_t)bt * 4096 + (size_t)t * 64) * D512;
    const float sc = 2.0f / 131072.0f;
#pragma unroll
    for (int ii = 0; ii < 4; ii++){
      const float4 vv = *(const float4*)(vbase + (size_t)(ty*4 + ii) * D512 + bcol + tx*4);
      float4 o;
      o.x = (acc[ii][0] - vv.x) * sc; o.y = (acc[ii][1] - vv.y) * sc;
      o.z = (acc[ii][2] - vv.z) * sc; o.w = (acc[ii][3] - vv.w) * sc;
      *(float4*)(ebuf + ((size_t)bt * 64 + ty*4 + ii) * D512 + bcol + tx*4) = o;
    }
  } else {
    float* rbase = ret + ((size_t)bt * 4096 + (size_t)t * 64) * D512;
#pragma unroll
    for (int ii = 0; ii < 4; ii++){
      float4 o; o.x=acc[ii][0]; o.y=acc[ii][1]; o.z=acc[ii][2]; o.w=acc[ii][3];
      *(float4*)(rbase + (size_t)(ty*4 + ii) * D512 + bcol + tx*4) = o;
    }
  }
}

// dpre = (ebuf @ W1) * silu'(pre0)   (NN matmul over m)
__global__ __launch_bounds__(256) void scan_dh(const float* __restrict__ ebuf,
                                               const float* __restrict__ W1,
                                               const float* __restrict__ pre0,
                                               float* __restrict__ dpre){
  __shared__ float As[BK][BM];
  __shared__ float Bs[BK][BN];
  const int tid = threadIdx.x, tx = tid & 15, ty = tid >> 4;
  const int bt = blockIdx.y;
  const float* Abase = ebuf + (size_t)bt * 64 * D512;
  const size_t bcol = (size_t)blockIdx.x * BN;
  float acc[4][4] = {};
  for (int k0 = 0; k0 < D512; k0 += BK){
    stage_nt(Abase + k0, As, tid);
    stage_nn(W1 + (size_t)k0 * D512 + bcol, Bs, tid);
    __syncthreads();
    mm_tile(As, Bs, acc, ty, tx);
    __syncthreads();
  }
#pragma unroll
  for (int ii = 0; ii < 4; ii++){
    const size_t off = ((size_t)bt * 64 + ty*4 + ii) * D512 + bcol + tx*4;
    const float4 p = *(const float4*)(pre0 + off);
    float4 o;
    o.x = acc[ii][0] * dsiluf_(p.x); o.y = acc[ii][1] * dsiluf_(p.y);
    o.z = acc[ii][2] * dsiluf_(p.z); o.w = acc[ii][3] * dsiluf_(p.w);
    *(float4*)(dpre + off) = o;
  }
}

// z=0: gW1[m,j] = sum_i e[i,m] hk[i,j]; update W1, mom1
// z=1: gW0[j,d] = sum_i dpre[i,j] k_chunk[i,d]; update W0, mom0
__global__ __launch_bounds__(256) void scan_grad_update(const float* __restrict__ ebuf,
                                                        const float* __restrict__ hk,
                                                        const float* __restrict__ dpre,
                                                        const float* __restrict__ kbuf,
                                                        float* __restrict__ W0, float* __restrict__ mom0,
                                                        float* __restrict__ W1, float* __restrict__ mom1,
                                                        const float* __restrict__ alpha,
                                                        const float* __restrict__ theta,
                                                        const float* __restrict__ eta, int t){
  __shared__ float Es[BK][BM];
  __shared__ float Hs[BK][BN];
  const int tid = threadIdx.x, tx = tid & 15, ty = tid >> 4;
  const int z = blockIdx.z;
  const float* E = (z == 0) ? ebuf : dpre;
  const size_t a0 = (size_t)blockIdx.y * BM;
  const size_t b0 = (size_t)blockIdx.x * BN;
  float acc[4][4] = {};
  for (int i0 = 0; i0 < 256; i0 += BK){
    stage_nn(E + (size_t)i0 * D512 + a0, Es, tid);
    const float* Hbase;
    if (z == 0) Hbase = hk + (size_t)i0 * D512 + b0;
    else        Hbase = kbuf + ((size_t)(i0 >> 6) * 4096 + (size_t)t * 64 + (i0 & 63)) * D512 + b0;
    stage_nn(Hbase, Hs, tid);
    __syncthreads();
    mm_tile(Es, Hs, acc, ty, tx);
    __syncthreads();
  }
  const float a = alpha[t], th = theta[t], et = eta[t];
  float* W  = (z == 0) ? W1 : W0;
  float* Mo = (z == 0) ? mom1 : mom0;
#pragma unroll
  for (int ii = 0; ii < 4; ii++){
    const size_t off = (a0 + ty*4 + ii) * D512 + b0 + tx*4;
    float4 m = *(float4*)(Mo + off);
    float4 w = *(float4*)(W + off);
    m.x = et*m.x - th*acc[ii][0]; m.y = et*m.y - th*acc[ii][1];
    m.z = et*m.z - th*acc[ii][2]; m.w = et*m.w - th*acc[ii][3];
    w.x = (1.0f - a)*w.x + m.x; w.y = (1.0f - a)*w.y + m.y;
    w.z = (1.0f - a)*w.z + m.z; w.w = (1.0f - a)*w.w + m.w;
    *(float4*)(Mo + off) = m;
    *(float4*)(W + off) = w;
  }
}

extern "C" void kernel_launch(void* const* d_in, const int* in_sizes, int n_in,
                              void* d_out, int out_size, void* d_ws, size_t ws_size,
                              hipStream_t stream) {
  const float* x    = (const float*)d_in[0];
  const float* Mb   = (const float*)d_in[1];
  const float* memW = (const float*)d_in[2];
  const float* Wk   = (const float*)d_in[3];
  const float* Wv   = (const float*)d_in[4];
  const float* Wq   = (const float*)d_in[5];
  const float* Wout = (const float*)d_in[6];
  const float* Wgd  = (const float*)d_in[7];
  const float* bgd  = (const float*)d_in[8];
  const float* Wgl  = (const float*)d_in[9];
  const float* bgl  = (const float*)d_in[10];
  const float* Wgm  = (const float*)d_in[11];
  const float* bgm  = (const float*)d_in[12];
  const float* gs   = (const float*)d_in[13];
  const float* gr   = (const float*)d_in[14];
  float* out = (float*)d_out;

  float* ws = (float*)d_ws;
  const size_t NBIG = (size_t)4 * 4096 * 512;      // 8388608
  float* xs   = ws;                                // x_store
  float* xr   = ws + NBIG;                         // rmsnorm(x,gr); later: retrieved
  float* xmq  = ws + 2 * NBIG;                     // xm; later: q
  float* kbuf = ws + 3 * NBIG;
  float* vbuf = ws + 4 * NBIG;
  float* cm   = ws + 5 * NBIG;                     // 131072
  float* pre0 = cm + 131072;
  float* hk   = pre0 + 131072;
  float* hq   = hk + 131072;
  float* ebuf = hq + 131072;
  float* dpre = ebuf + 131072;
  float* W0   = dpre + 131072;                     // 262144
  float* W1   = W0 + 262144;
  float* mom  = W1 + 262144;                       // mom0 + mom1 = 524288
  float* mom0 = mom;
  float* mom1 = mom + 262144;
  float* alpha = mom + 524288;                     // 64
  float* theta = alpha + 64;
  float* eta   = theta + 64;

  // init weight state
  hipMemcpyAsync(W0, memW, 2 * 262144 * sizeof(float), hipMemcpyDeviceToDevice, stream);
  hipMemsetAsync(mom, 0, 2 * 262144 * sizeof(float), stream);

  // pre-scan
  rmsnorm2_kernel<<<16384, 128, 0, stream>>>(x, gs, gr, xs, xr);
  chunk_mean_kernel<<<dim3(64, 4), 128, 0, stream>>>(x, cm);
  gates_kernel<<<64, 256, 0, stream>>>(cm, Wgd, bgd, Wgl, bgl, Wgm, bgm, alpha, theta, eta);

  gemm_nn_batched<<<dim3(8, 64, 4), 256, 0, stream>>>(xs, Mb, xmq);         // xm = x_store @ M[b]
  gemm_nt<true><<<dim3(8, 256), 256, 0, stream>>>(xmq, Wk, kbuf);           // silu(xm @ Wk^T)
  l2norm_kernel<<<16384, 128, 0, stream>>>(kbuf);                           // k
  gemm_nt<true><<<dim3(8, 256), 256, 0, stream>>>(xs, Wv, vbuf);            // v
  gemm_nt<true><<<dim3(8, 256), 256, 0, stream>>>(xr, Wq, xmq);             // silu(xr @ Wq^T)
  l2norm_kernel<<<16384, 128, 0, stream>>>(xmq);                            // q (in xmq)

  // scan: 64 sequential chunks; retrieved -> xr
  for (int t = 0; t < 64; t++){
    scan_fw0<<<dim3(8, 4, 2), 256, 0, stream>>>(kbuf, xmq, W0, pre0, hk, hq, t);
    scan_fw1<<<dim3(8, 4, 2), 256, 0, stream>>>(hk, hq, W1, vbuf, ebuf, xr, t);
    scan_dh<<<dim3(8, 4), 256, 0, stream>>>(ebuf, W1, pre0, dpre);
    scan_grad_update<<<dim3(8, 8, 2), 256, 0, stream>>>(ebuf, hk, dpre, kbuf,
                                                        W0, mom0, W1, mom1,
                                                        alpha, theta, eta, t);
  }

  // out = retrieved @ Wout^T
  gemm_nt<false><<<dim3(8, 256), 256, 0, stream>>>(xr, Wout, out);
}

// Round 2
// 5657.827 us; speedup vs baseline: 1.3711x; 1.3711x over previous
//
#include <hip/hip_runtime.h>
#include <math.h>
#include <stdint.h>

#define D512 512
#define SC_E (2.0f / 131072.0f)

typedef __attribute__((ext_vector_type(8))) __bf16 bf16x8;
typedef __attribute__((ext_vector_type(4))) float f32x4;
#define MFMA(a,b,c) __builtin_amdgcn_mfma_f32_16x16x32_bf16(a,b,c,0,0,0)

__device__ __forceinline__ float sigmoidf_(float z){ return 1.0f/(1.0f+expf(-z)); }
__device__ __forceinline__ float siluf_(float z){ return z/(1.0f+expf(-z)); }
__device__ __forceinline__ float dsiluf_(float z){ float s=1.0f/(1.0f+expf(-z)); return s*(1.0f+z*(1.0f-s)); }

__device__ __forceinline__ unsigned short f2bf(float x){
  union { float f; unsigned u; } c; c.f = x;
  unsigned r = (c.u + 0x7fffu + ((c.u >> 16) & 1u)) >> 16;
  return (unsigned short)r;
}
__device__ __forceinline__ float bf2f(unsigned short s){
  union { unsigned u; float f; } c; c.u = ((unsigned)s) << 16; return c.f;
}
__device__ __forceinline__ void split2(float x, unsigned short& h, unsigned short& l){
  h = f2bf(x); l = f2bf(x - bf2f(h));
}
__device__ __forceinline__ bf16x8 ldf(const unsigned short* p){ return *(const bf16x8*)p; }

// ---------- MFMA 64x64 tile primitives (block=256 thr=4 waves; wave w -> rows [w*16,w*16+16)) ----------
// A-frag: A[m=lane&15][k=(lane>>4)*8+j]; B-frag: B[n=lane&15][k=(lane>>4)*8+j]
// C/D: col=lane&15, row=(lane>>4)*4+reg.   All verified layouts (learn_hip m89/m91/m120).
template<int KTOT>
__device__ __forceinline__ void tile_ss(const unsigned short* __restrict__ A, int lda,
                                        const unsigned short* __restrict__ B, int ldb,
                                        f32x4* acc){
  const int lane = threadIdx.x & 63, wave = threadIdx.x >> 6;
  const int kq = (lane >> 4) << 3;
  const size_t aoff = (size_t)(wave*16 + (lane & 15)) * lda + kq;
  const size_t boff0 = (size_t)(lane & 15) * ldb + kq;
#pragma unroll
  for (int k0 = 0; k0 < KTOT; k0 += 32){
    bf16x8 av = ldf(A + aoff + k0);
#pragma unroll
    for (int nn = 0; nn < 4; nn++){
      bf16x8 bv = ldf(B + boff0 + (size_t)(nn*16)*ldb + k0);
      acc[nn] = MFMA(av, bv, acc[nn]);
    }
  }
}

template<int KTOT>
__device__ __forceinline__ void tile_dd(const unsigned short* __restrict__ Ah, const unsigned short* __restrict__ Al, int lda,
                                        const unsigned short* __restrict__ Bh, const unsigned short* __restrict__ Bl, int ldb,
                                        f32x4* acc){
  const int lane = threadIdx.x & 63, wave = threadIdx.x >> 6;
  const int kq = (lane >> 4) << 3;
  const size_t aoff = (size_t)(wave*16 + (lane & 15)) * lda + kq;
  const size_t boff0 = (size_t)(lane & 15) * ldb + kq;
#pragma unroll
  for (int k0 = 0; k0 < KTOT; k0 += 32){
    bf16x8 ah = ldf(Ah + aoff + k0);
    bf16x8 al = ldf(Al + aoff + k0);
#pragma unroll
    for (int nn = 0; nn < 4; nn++){
      const size_t bo = boff0 + (size_t)(nn*16)*ldb + k0;
      bf16x8 bh = ldf(Bh + bo);
      bf16x8 bl = ldf(Bl + bo);
      acc[nn] = MFMA(ah, bh, acc[nn]);
      acc[nn] = MFMA(ah, bl, acc[nn]);
      acc[nn] = MFMA(al, bh, acc[nn]);
    }
  }
}

// ---------- elementwise / pre kernels ----------
__global__ void rms_store_kernel(const float* __restrict__ x, const float* __restrict__ g,
                                 unsigned short* __restrict__ dstH){
  const size_t row = blockIdx.x; const int tid = threadIdx.x; // 128 thr
  const float4 xv = *(const float4*)(x + row * D512 + tid * 4);
  float ss = xv.x*xv.x + xv.y*xv.y + xv.z*xv.z + xv.w*xv.w;
  for (int o = 32; o > 0; o >>= 1) ss += __shfl_xor(ss, o, 64);
  __shared__ float w2[2];
  if ((tid & 63) == 0) w2[tid >> 6] = ss;
  __syncthreads();
  const float r = rsqrtf((w2[0] + w2[1]) * (1.0f / 512.0f) + 1.1920929e-07f);
  const float4 gv = *(const float4*)(g + tid * 4);
  ushort4 h;
  h.x = f2bf(xv.x*r*gv.x); h.y = f2bf(xv.y*r*gv.y); h.z = f2bf(xv.z*r*gv.z); h.w = f2bf(xv.w*r*gv.w);
  *(ushort4*)(dstH + row * D512 + tid * 4) = h;
}

__global__ void rms_retr_kernel(const float* __restrict__ x, const float* __restrict__ g,
                                unsigned short* __restrict__ dstH, unsigned short* __restrict__ dstL){
  const size_t row = blockIdx.x; const int tid = threadIdx.x; // 128 thr
  const float4 xv = *(const float4*)(x + row * D512 + tid * 4);
  float ss = xv.x*xv.x + xv.y*xv.y + xv.z*xv.z + xv.w*xv.w;
  for (int o = 32; o > 0; o >>= 1) ss += __shfl_xor(ss, o, 64);
  __shared__ float w2[2];
  if ((tid & 63) == 0) w2[tid >> 6] = ss;
  __syncthreads();
  const float r = rsqrtf((w2[0] + w2[1]) * (1.0f / 512.0f) + 1.1920929e-07f);
  const float4 gv = *(const float4*)(g + tid * 4);
  float v0 = xv.x*r*gv.x, v1 = xv.y*r*gv.y, v2 = xv.z*r*gv.z, v3 = xv.w*r*gv.w;
  ushort4 h, l;
  split2(v0, h.x, l.x); split2(v1, h.y, l.y); split2(v2, h.z, l.z); split2(v3, h.w, l.w);
  *(ushort4*)(dstH + row * D512 + tid * 4) = h;
  *(ushort4*)(dstL + row * D512 + tid * 4) = l;
}

__global__ void l2norm_split_kernel(float* __restrict__ buf,
                                    unsigned short* __restrict__ dstH, unsigned short* __restrict__ dstL){
  const size_t row = blockIdx.x; const int tid = threadIdx.x; // 128 thr
  float4 xv = *(const float4*)(buf + row * D512 + tid * 4);
  float ss = xv.x*xv.x + xv.y*xv.y + xv.z*xv.z + xv.w*xv.w;
  for (int o = 32; o > 0; o >>= 1) ss += __shfl_xor(ss, o, 64);
  __shared__ float w2[2];
  if ((tid & 63) == 0) w2[tid >> 6] = ss;
  __syncthreads();
  const float n = sqrtf(w2[0] + w2[1]);
  const float sc = 1.0f / fmaxf(n, 1e-12f);
  xv.x *= sc; xv.y *= sc; xv.z *= sc; xv.w *= sc;
  *(float4*)(buf + row * D512 + tid * 4) = xv;
  ushort4 h; h.x = f2bf(xv.x); h.y = f2bf(xv.y); h.z = f2bf(xv.z); h.w = f2bf(xv.w);
  *(ushort4*)(dstH + row * D512 + tid * 4) = h;
  if (dstL){
    ushort4 l;
    l.x = f2bf(xv.x - bf2f(h.x)); l.y = f2bf(xv.y - bf2f(h.y));
    l.z = f2bf(xv.z - bf2f(h.z)); l.w = f2bf(xv.w - bf2f(h.w));
    *(ushort4*)(dstL + row * D512 + tid * 4) = l;
  }
}

__global__ void cast_kernel(const float* __restrict__ src, unsigned short* __restrict__ dstH,
                            unsigned short* __restrict__ dstL, int n){
  int i = (blockIdx.x * 256 + threadIdx.x) * 4;
  if (i >= n) return;
  float4 v = *(const float4*)(src + i);
  ushort4 h; h.x = f2bf(v.x); h.y = f2bf(v.y); h.z = f2bf(v.z); h.w = f2bf(v.w);
  *(ushort4*)(dstH + i) = h;
  if (dstL){
    ushort4 l;
    l.x = f2bf(v.x - bf2f(h.x)); l.y = f2bf(v.y - bf2f(h.y));
    l.z = f2bf(v.z - bf2f(h.z)); l.w = f2bf(v.w - bf2f(h.w));
    *(ushort4*)(dstL + i) = l;
  }
}

// transpose fp32 [R][C] -> bf16 (single/split) [C][R]; grid(C/64, R/64, batches)
__global__ void trans_cast_kernel(const float* __restrict__ src, unsigned short* __restrict__ dstH,
                                  unsigned short* __restrict__ dstL, int R, int C,
                                  size_t sbs, size_t dbs){
  __shared__ float t[64][65];
  const int b = blockIdx.z;
  const float* s = src + (size_t)b * sbs;
  const int r0 = blockIdx.y * 64, c0 = blockIdx.x * 64;
  for (int i = threadIdx.x; i < 4096; i += 256){
    int rr = i >> 6, cc = i & 63;
    t[rr][cc] = s[(size_t)(r0 + rr) * C + c0 + cc];
  }
  __syncthreads();
  for (int i = threadIdx.x; i < 4096; i += 256){
    int cc = i >> 6, rr = i & 63;
    float v = t[rr][cc];
    size_t off = (size_t)b * dbs + (size_t)(c0 + cc) * R + r0 + rr;
    unsigned short h = f2bf(v);
    dstH[off] = h;
    if (dstL) dstL[off] = f2bf(v - bf2f(h));
  }
}

__global__ void chunk_mean_kernel(const float* __restrict__ x, float* __restrict__ cm){
  const int c = blockIdx.x, b = blockIdx.y, tid = threadIdx.x; // 128 threads
  const float* base = x + ((size_t)b * 4096 + (size_t)c * 64) * D512 + tid * 4;
  float4 s = {0,0,0,0};
  for (int r = 0; r < 64; r++){
    const float4 v = *(const float4*)(base + (size_t)r * D512);
    s.x += v.x; s.y += v.y; s.z += v.z; s.w += v.w;
  }
  const float inv = 1.0f / 64.0f;
  s.x *= inv; s.y *= inv; s.z *= inv; s.w *= inv;
  *(float4*)(cm + ((size_t)b * 64 + c) * D512 + tid * 4) = s;
}

__global__ void gates_kernel(const float* __restrict__ cm,
                             const float* __restrict__ Wgd, const float* __restrict__ bgd,
                             const float* __restrict__ Wgl, const float* __restrict__ bgl,
                             const float* __restrict__ Wgm, const float* __restrict__ bgm,
                             float* __restrict__ alpha, float* __restrict__ theta, float* __restrict__ eta){
  const int c = blockIdx.x, tid = threadIdx.x; // 256 threads
  __shared__ float cmsh[512];
  float s0 = 0.f, s1 = 0.f, s2 = 0.f;
  for (int b = 0; b < 4; b++){
    __syncthreads();
    if (tid < 128){
      const float4 v = *(const float4*)(cm + ((size_t)b * 64 + c) * D512 + tid * 4);
      *(float4*)&cmsh[tid * 4] = v;
    }
    __syncthreads();
    for (int j = tid; j < 512; j += 256){
      float d0 = bgd[j], d1 = bgl[j], d2 = bgm[j];
      const float* w0 = Wgd + (size_t)j * D512;
      const float* w1 = Wgl + (size_t)j * D512;
      const float* w2 = Wgm + (size_t)j * D512;
      for (int kk = 0; kk < 512; kk += 4){
        const float4 cv = *(const float4*)&cmsh[kk];
        const float4 a = *(const float4*)(w0 + kk); d0 += cv.x*a.x + cv.y*a.y + cv.z*a.z + cv.w*a.w;
        const float4 e = *(const float4*)(w1 + kk); d1 += cv.x*e.x + cv.y*e.y + cv.z*e.z + cv.w*e.w;
        const float4 g = *(const float4*)(w2 + kk); d2 += cv.x*g.x + cv.y*g.y + cv.z*g.z + cv.w*g.w;
      }
      s0 += sigmoidf_(d0); s1 += sigmoidf_(d1); s2 += sigmoidf_(d2);
    }
  }
  __shared__ float red[256];
  const float inv = 1.0f / 2048.0f;
  red[tid] = s0; __syncthreads();
  for (int o = 128; o > 0; o >>= 1){ if (tid < o) red[tid] += red[tid + o]; __syncthreads(); }
  if (tid == 0) alpha[c] = red[0] * inv * 0.01f;
  __syncthreads();
  red[tid] = s1; __syncthreads();
  for (int o = 128; o > 0; o >>= 1){ if (tid < o) red[tid] += red[tid + o]; __syncthreads(); }
  if (tid == 0) theta[c] = red[0] * inv * 0.1f;
  __syncthreads();
  red[tid] = s2; __syncthreads();
  for (int o = 128; o > 0; o >>= 1){ if (tid < o) red[tid] += red[tid + o]; __syncthreads(); }
  if (tid == 0) eta[c] = red[0] * inv * 0.9f;
}

// ---------- big MFMA GEMMs (NT: C[i,j] = sum_k A[i,k] B[j,k]) ----------
// MODE 0: out bf16 single plane, no act. MODE 1: out fp32 + silu. MODE 2: out fp32, no act.
template<int MODE>
__global__ __launch_bounds__(256) void gemm_ss(const unsigned short* __restrict__ A,
                                               const unsigned short* __restrict__ B, size_t bzs,
                                               void* __restrict__ out){
  const int lane = threadIdx.x & 63, wave = threadIdx.x >> 6;
  const int er = wave*16 + ((lane >> 4) << 2), ec = lane & 15;
  const size_t row0 = (size_t)blockIdx.z * 4096 + (size_t)blockIdx.y * 64;
  const int n0 = blockIdx.x * 64;
  f32x4 acc[4] = {};
  tile_ss<512>(A + row0 * D512, D512, B + (size_t)blockIdx.z * bzs + (size_t)n0 * D512, D512, acc);
#pragma unroll
  for (int nn = 0; nn < 4; nn++)
#pragma unroll
    for (int r = 0; r < 4; r++){
      const size_t off = (row0 + er + r) * D512 + n0 + nn*16 + ec;
      float val = acc[nn][r];
      if (MODE == 0) ((unsigned short*)out)[off] = f2bf(val);
      else if (MODE == 1) ((float*)out)[off] = siluf_(val);
      else ((float*)out)[off] = val;
    }
}

// split x split (3-MFMA). MODE 1: fp32 silu. MODE 2: fp32 plain.
template<int MODE>
__global__ __launch_bounds__(256) void gemm_dd(const unsigned short* __restrict__ Ah, const unsigned short* __restrict__ Al,
                                               const unsigned short* __restrict__ Bh, const unsigned short* __restrict__ Bl,
                                               float* __restrict__ out){
  const int lane = threadIdx.x & 63, wave = threadIdx.x >> 6;
  const int er = wave*16 + ((lane >> 4) << 2), ec = lane & 15;
  const size_t row0 = (size_t)blockIdx.y * 64;
  const int n0 = blockIdx.x * 64;
  f32x4 acc[4] = {};
  tile_dd<512>(Ah + row0 * D512, Al + row0 * D512, D512,
               Bh + (size_t)n0 * D512, Bl + (size_t)n0 * D512, D512, acc);
#pragma unroll
  for (int nn = 0; nn < 4; nn++)
#pragma unroll
    for (int r = 0; r < 4; r++){
      const size_t off = (row0 + er + r) * D512 + n0 + nn*16 + ec;
      out[off] = (MODE == 1) ? siluf_(acc[nn][r]) : acc[nn][r];
    }
}

// ---------- scan kernels ----------
// Phase A: a1 hk = silu(k@W0^T) [i][j]; a2 hkT = silu(W0@k^T) [j][i] + s'T; a3 hq split.
__global__ __launch_bounds__(256) void scanA(const unsigned short* __restrict__ kbH,
                                             const unsigned short* __restrict__ qbH, const unsigned short* __restrict__ qbL,
                                             const unsigned short* __restrict__ W0bH, const unsigned short* __restrict__ W0bL,
                                             unsigned short* __restrict__ hkbH, unsigned short* __restrict__ hkTbH,
                                             float* __restrict__ spT,
                                             unsigned short* __restrict__ hqbH, unsigned short* __restrict__ hqbL, int t){
  const int part = blockIdx.x >> 5, sub = blockIdx.x & 31;
  const int lane = threadIdx.x & 63, wave = threadIdx.x >> 6;
  const int er = wave*16 + ((lane >> 4) << 2), ec = lane & 15;
  f32x4 acc[4] = {};
  if (part == 0){
    const int bt = sub >> 3, nx = sub & 7;
    tile_ss<512>(kbH + ((size_t)bt*4096 + (size_t)t*64) * D512, D512,
                 W0bH + (size_t)nx*64 * D512, D512, acc);
#pragma unroll
    for (int nn = 0; nn < 4; nn++)
#pragma unroll
      for (int r = 0; r < 4; r++){
        const int i = bt*64 + er + r, j = nx*64 + nn*16 + ec;
        hkbH[(size_t)i * D512 + j] = f2bf(siluf_(acc[nn][r]));
      }
  } else if (part == 1){
    const int jx = sub >> 2, ib = sub & 3;
    tile_ss<512>(W0bH + (size_t)jx*64 * D512, D512,
                 kbH + ((size_t)ib*4096 + (size_t)t*64) * D512, D512, acc);
#pragma unroll
    for (int nn = 0; nn < 4; nn++)
#pragma unroll
      for (int r = 0; r < 4; r++){
        const int j = jx*64 + er + r, i = ib*64 + nn*16 + ec;
        const size_t off = (size_t)j * 256 + i;
        const float p = acc[nn][r];
        hkTbH[off] = f2bf(siluf_(p));
        spT[off] = dsiluf_(p);
      }
  } else {
    const int bt = sub >> 3, nx = sub & 7;
    const size_t abase = ((size_t)bt*4096 + (size_t)t*64) * D512;
    tile_dd<512>(qbH + abase, qbL + abase, D512,
                 W0bH + (size_t)nx*64 * D512, W0bL + (size_t)nx*64 * D512, D512, acc);
#pragma unroll
    for (int nn = 0; nn < 4; nn++)
#pragma unroll
      for (int r = 0; r < 4; r++){
        const int i = bt*64 + er + r, j = nx*64 + nn*16 + ec;
        const size_t off = (size_t)i * D512 + j;
        const float h = siluf_(acc[nn][r]);
        unsigned short hh, ll; split2(h, hh, ll);
        hqbH[off] = hh; hqbL[off] = ll;
      }
  }
}

// Phase B: b1 e [i][m]; b2 eT [m][i]; b3 ret split (global rows).
__global__ __launch_bounds__(256) void scanB(const unsigned short* __restrict__ hkbH,
                                             const unsigned short* __restrict__ hqbH, const unsigned short* __restrict__ hqbL,
                                             const unsigned short* __restrict__ W1bH, const unsigned short* __restrict__ W1bL,
                                             const float* __restrict__ v,
                                             unsigned short* __restrict__ ebH, unsigned short* __restrict__ eTbH,
                                             unsigned short* __restrict__ retH, unsigned short* __restrict__ retL, int t){
  const int part = blockIdx.x >> 5, sub = blockIdx.x & 31;
  const int lane = threadIdx.x & 63, wave = threadIdx.x >> 6;
  const int er = wave*16 + ((lane >> 4) << 2), ec = lane & 15;
  f32x4 acc[4] = {};
  if (part == 0){
    const int bt = sub >> 3, nx = sub & 7;
    tile_ss<512>(hkbH + (size_t)bt*64 * D512, D512, W1bH + (size_t)nx*64 * D512, D512, acc);
#pragma unroll
    for (int nn = 0; nn < 4; nn++)
#pragma unroll
      for (int r = 0; r < 4; r++){
        const int il = er + r, m = nx*64 + nn*16 + ec;
        const float vv = v[((size_t)bt*4096 + (size_t)t*64 + il) * D512 + m];
        ebH[(size_t)(bt*64 + il) * D512 + m] = f2bf((acc[nn][r] - vv) * SC_E);
      }
  } else if (part == 1){
    const int jx = sub >> 2, ib = sub & 3;
    tile_ss<512>(W1bH + (size_t)jx*64 * D512, D512, hkbH + (size_t)ib*64 * D512, D512, acc);
#pragma unroll
    for (int nn = 0; nn < 4; nn++)
#pragma unroll
      for (int r = 0; r < 4; r++){
        const int m = jx*64 + er + r, il = nn*16 + ec;
        const float vv = v[((size_t)ib*4096 + (size_t)t*64 + il) * D512 + m];
        eTbH[(size_t)m * 256 + ib*64 + il] = f2bf((acc[nn][r] - vv) * SC_E);
      }
  } else {
    const int bt = sub >> 3, nx = sub & 7;
    tile_dd<512>(hqbH + (size_t)bt*64 * D512, hqbL + (size_t)bt*64 * D512, D512,
                 W1bH + (size_t)nx*64 * D512, W1bL + (size_t)nx*64 * D512, D512, acc);
#pragma unroll
    for (int nn = 0; nn < 4; nn++)
#pragma unroll
      for (int r = 0; r < 4; r++){
        const size_t off = ((size_t)bt*4096 + (size_t)t*64 + er + r) * D512 + nx*64 + nn*16 + ec;
        unsigned short hh, ll; split2(acc[nn][r], hh, ll);
        retH[off] = hh; retL[off] = ll;
      }
  }
}

// Phase C: c1 dpT[j][i] = (W1T @ e^T layout-free) * s'T ; c2 mom1 update from gW1.
__global__ __launch_bounds__(256) void scanC(const unsigned short* __restrict__ W1TbH,
                                             const unsigned short* __restrict__ ebH, const float* __restrict__ spT,
                                             const unsigned short* __restrict__ eTbH, const unsigned short* __restrict__ hkTbH,
                                             unsigned short* __restrict__ dpTbH, float* __restrict__ mom1,
                                             const float* __restrict__ theta, const float* __restrict__ eta, int t){
  const int lane = threadIdx.x & 63, wave = threadIdx.x >> 6;
  const int er = wave*16 + ((lane >> 4) << 2), ec = lane & 15;
  f32x4 acc[4] = {};
  if (blockIdx.x < 32){
    const int jx = blockIdx.x >> 2, ib = blockIdx.x & 3;
    tile_ss<512>(W1TbH + (size_t)jx*64 * D512, D512, ebH + (size_t)ib*64 * D512, D512, acc);
#pragma unroll
    for (int nn = 0; nn < 4; nn++)
#pragma unroll
      for (int r = 0; r < 4; r++){
        const int j = jx*64 + er + r, i = ib*64 + nn*16 + ec;
        const size_t off = (size_t)j * 256 + i;
        dpTbH[off] = f2bf(acc[nn][r] * spT[off]);
      }
  } else {
    const int s = blockIdx.x - 32;
    const int mx = s >> 3, jx = s & 7;
    tile_ss<256>(eTbH + (size_t)mx*64 * 256, 256, hkTbH + (size_t)jx*64 * 256, 256, acc);
    const float th = theta[t], et = eta[t];
#pragma unroll
    for (int nn = 0; nn < 4; nn++)
#pragma unroll
      for (int r = 0; r < 4; r++){
        const size_t off = (size_t)(mx*64 + er + r) * D512 + jx*64 + nn*16 + ec;
        mom1[off] = et * mom1[off] - th * acc[nn][r];
      }
  }
}

// Phase D: gW0 -> mom0/W0 update + W0b recast; W1 update from mom1 + W1b/W1Tb recast.
__global__ __launch_bounds__(256) void scanD(const unsigned short* __restrict__ dpTbH,
                                             const unsigned short* __restrict__ kTbH,
                                             float* __restrict__ W0f, float* __restrict__ mom0,
                                             unsigned short* __restrict__ W0bH, unsigned short* __restrict__ W0bL,
                                             float* __restrict__ W1f, const float* __restrict__ mom1,
                                             unsigned short* __restrict__ W1bH, unsigned short* __restrict__ W1bL,
                                             unsigned short* __restrict__ W1TbH,
                                             const float* __restrict__ alpha, const float* __restrict__ theta,
                                             const float* __restrict__ eta, int t){
  const int s = blockIdx.x;
  const int jx = s >> 3, dx = s & 7;
  const int lane = threadIdx.x & 63, wave = threadIdx.x >> 6;
  const int er = wave*16 + ((lane >> 4) << 2), ec = lane & 15;
  const int kq = (lane >> 4) << 3;
  f32x4 acc[4] = {};
  const unsigned short* a = dpTbH + (size_t)(jx*64 + wave*16 + (lane & 15)) * 256 + kq;
#pragma unroll
  for (int k0 = 0; k0 < 256; k0 += 32){
    bf16x8 av = ldf(a + k0);
    const int pl = k0 >> 6;
    const unsigned short* bB = kTbH + (size_t)pl * (512*4096) + (size_t)t*64 + (k0 & 63) + kq;
#pragma unroll
    for (int nn = 0; nn < 4; nn++){
      bf16x8 bv = ldf(bB + (size_t)(dx*64 + nn*16 + (lane & 15)) * 4096);
      acc[nn] = MFMA(av, bv, acc[nn]);
    }
  }
  const float al = alpha[t], th = theta[t], et = eta[t];
#pragma unroll
  for (int nn = 0; nn < 4; nn++)
#pragma unroll
    for (int r = 0; r < 4; r++){
      const size_t off = (size_t)(jx*64 + er + r) * D512 + dx*64 + nn*16 + ec;
      float m = et * mom0[off] - th * acc[nn][r];
      mom0[off] = m;
      float w = (1.0f - al) * W0f[off] + m;
      W0f[off] = w;
      unsigned short hh, ll; split2(w, hh, ll);
      W0bH[off] = hh; W0bL[off] = ll;
    }
  // W1 state update (mom1 finalized in phase C)
  for (int idx = threadIdx.x; idx < 4096; idx += 256){
    const int rr = idx >> 6, cc = idx & 63;
    const int m = jx*64 + rr, j = dx*64 + cc;
    const size_t off = (size_t)m * D512 + j;
    float w1 = (1.0f - al) * W1f[off] + mom1[off];
    W1f[off] = w1;
    unsigned short hh, ll; split2(w1, hh, ll);
    W1bH[off] = hh; W1bL[off] = ll;
    W1TbH[(size_t)j * D512 + m] = hh;
  }
}

// ---------------- launcher ----------------
extern "C" void kernel_launch(void* const* d_in, const int* in_sizes, int n_in,
                              void* d_out, int out_size, void* d_ws, size_t ws_size,
                              hipStream_t stream) {
  const float* x    = (const float*)d_in[0];
  const float* Mb   = (const float*)d_in[1];
  const float* memW = (const float*)d_in[2];
  const float* Wk   = (const float*)d_in[3];
  const float* Wv   = (const float*)d_in[4];
  const float* Wq   = (const float*)d_in[5];
  const float* Wout = (const float*)d_in[6];
  const float* Wgd  = (const float*)d_in[7];
  const float* bgd  = (const float*)d_in[8];
  const float* Wgl  = (const float*)d_in[9];
  const float* bgl  = (const float*)d_in[10];
  const float* Wgm  = (const float*)d_in[11];
  const float* bgm  = (const float*)d_in[12];
  const float* gs   = (const float*)d_in[13];
  const float* gr   = (const float*)d_in[14];
  float* out = (float*)d_out;

  const size_t NBIG = (size_t)4 * 4096 * 512;   // 8388608 elems
  char* p = (char*)d_ws;
  auto alloc_f = [&](size_t n) -> float* {
    p = (char*)(((uintptr_t)p + 255) & ~(uintptr_t)255);
    float* r = (float*)p; p += n * 4; return r;
  };
  auto alloc_s = [&](size_t n) -> unsigned short* {
    p = (char*)(((uintptr_t)p + 255) & ~(uintptr_t)255);
    unsigned short* r = (unsigned short*)p; p += n * 2; return r;
  };

  float* v       = alloc_f(NBIG);
  float* scratch = alloc_f(NBIG);
  float* W0f     = alloc_f(262144);
  float* W1f     = alloc_f(262144);   // must directly follow W0f (single memcpy)
  float* mom0    = alloc_f(262144);
  float* mom1    = alloc_f(262144);   // must directly follow mom0 (single memset)
  float* spT     = alloc_f(131072);
  float* cm      = alloc_f(131072);
  float* alpha   = alloc_f(64);
  float* theta   = alloc_f(64);
  float* eta     = alloc_f(64);

  unsigned short* xsbH = alloc_s(NBIG);   // x_store single; reused as retH during scan
  unsigned short* xmbH = alloc_s(NBIG);   // xm single; reused as xrbH then retL
  unsigned short* xrbL = alloc_s(NBIG);
  unsigned short* qbH  = alloc_s(NBIG);
  unsigned short* qbL  = alloc_s(NBIG);
  unsigned short* kbH  = alloc_s(NBIG);
  unsigned short* kTbH = alloc_s(NBIG);   // [4][512][4096]
  unsigned short* W0bH = alloc_s(262144);
  unsigned short* W0bL = alloc_s(262144);
  unsigned short* W1bH = alloc_s(262144);
  unsigned short* W1bL = alloc_s(262144);
  unsigned short* W1TbH = alloc_s(262144);
  unsigned short* WkbH = alloc_s(262144);
  unsigned short* WvbH = alloc_s(262144);
  unsigned short* WqbH = alloc_s(262144);
  unsigned short* WqbL = alloc_s(262144);
  unsigned short* WoutbH = alloc_s(262144);
  unsigned short* WoutbL = alloc_s(262144);
  unsigned short* MTbH = alloc_s((size_t)4 * 262144);
  unsigned short* hkbH = alloc_s(131072);
  unsigned short* hkTbH = alloc_s(131072);
  unsigned short* hqbH = alloc_s(131072);
  unsigned short* hqbL = alloc_s(131072);
  unsigned short* ebH  = alloc_s(131072);
  unsigned short* eTbH = alloc_s(131072);
  unsigned short* dpTbH = alloc_s(131072);

  // ---- weight state init ----
  hipMemcpyAsync(W0f, memW, 2 * 262144 * sizeof(float), hipMemcpyDeviceToDevice, stream);
  hipMemsetAsync(mom0, 0, 2 * 262144 * sizeof(float), stream);
  cast_kernel<<<256, 256, 0, stream>>>(memW, W0bH, W0bL, 262144);
  cast_kernel<<<256, 256, 0, stream>>>(memW + 262144, W1bH, W1bL, 262144);
  trans_cast_kernel<<<dim3(8, 8, 1), 256, 0, stream>>>(memW + 262144, W1TbH, nullptr, 512, 512, 0, 0);
  cast_kernel<<<256, 256, 0, stream>>>(Wk, WkbH, nullptr, 262144);
  cast_kernel<<<256, 256, 0, stream>>>(Wv, WvbH, nullptr, 262144);
  cast_kernel<<<256, 256, 0, stream>>>(Wq, WqbH, WqbL, 262144);
  cast_kernel<<<256, 256, 0, stream>>>(Wout, WoutbH, WoutbL, 262144);
  trans_cast_kernel<<<dim3(8, 8, 4), 256, 0, stream>>>(Mb, MTbH, nullptr, 512, 512, 262144, 262144);

  // ---- pre-scan ----
  rms_store_kernel<<<16384, 128, 0, stream>>>(x, gs, xsbH);
  chunk_mean_kernel<<<dim3(64, 4), 128, 0, stream>>>(x, cm);
  gates_kernel<<<64, 256, 0, stream>>>(cm, Wgd, bgd, Wgl, bgl, Wgm, bgm, alpha, theta, eta);

  gemm_ss<0><<<dim3(8, 64, 4), 256, 0, stream>>>(xsbH, MTbH, 262144, xmbH);        // xm (bf16)
  gemm_ss<1><<<dim3(8, 256, 1), 256, 0, stream>>>(xmbH, WkbH, 0, scratch);         // silu(xm@Wk^T)
  l2norm_split_kernel<<<16384, 128, 0, stream>>>(scratch, kbH, nullptr);           // k
  trans_cast_kernel<<<dim3(8, 64, 4), 256, 0, stream>>>(scratch, kTbH, nullptr, 4096, 512, 2097152, 2097152); // kT
  gemm_ss<1><<<dim3(8, 256, 1), 256, 0, stream>>>(xsbH, WvbH, 0, v);               // v
  rms_retr_kernel<<<16384, 128, 0, stream>>>(x, gr, xmbH, xrbL);                   // xr split (xmbH reused)
  gemm_dd<1><<<dim3(8, 256), 256, 0, stream>>>(xmbH, xrbL, WqbH, WqbL, scratch);   // silu(xr@Wq^T)
  l2norm_split_kernel<<<16384, 128, 0, stream>>>(scratch, qbH, qbL);               // q split

  unsigned short* retH = xsbH;  // free after v-gemm
  unsigned short* retL = xmbH;  // free after q-gemm

  // ---- scan ----
  for (int t = 0; t < 64; t++){
    scanA<<<96, 256, 0, stream>>>(kbH, qbH, qbL, W0bH, W0bL, hkbH, hkTbH, spT, hqbH, hqbL, t);
    scanB<<<96, 256, 0, stream>>>(hkbH, hqbH, hqbL, W1bH, W1bL, v, ebH, eTbH, retH, retL, t);
    scanC<<<96, 256, 0, stream>>>(W1TbH, ebH, spT, eTbH, hkTbH, dpTbH, mom1, theta, eta, t);
    scanD<<<64, 256, 0, stream>>>(dpTbH, kTbH, W0f, mom0, W0bH, W0bL,
                                  W1f, mom1, W1bH, W1bL, W1TbH, alpha, theta, eta, t);
  }

  // ---- post: out = retrieved @ Wout^T (split x split) ----
  gemm_dd<2><<<dim3(8, 256), 256, 0, stream>>>(retH, retL, WoutbH, WoutbL, out);
}